// Round 3
// baseline (42.976 us; speedup 1.0000x reference)
//
#include <hip/hip_runtime.h>
#include <hip/hip_bf16.h>

#define B_   16
#define NC_  1024
#define NQ_  128
#define D_   512

typedef __attribute__((ext_vector_type(8))) short bf16x8;
typedef __attribute__((ext_vector_type(4))) float f32x4;

// fp32 -> bf16 RTNE; scalar cast so compiler can fuse pairs into v_cvt_pk_bf16_f32
__device__ __forceinline__ short f2bf(float x) {
    return __builtin_bit_cast(short, __float2bfloat16(x));
}

// Pre-kernel: qw[b][j][d] = bf16(q * w_cq); qterm[b][j] = q . w_q (fp32); wcb = bf16(w_c)
__global__ __launch_bounds__(256) void prep_kernel(
    const float* __restrict__ q, const float* __restrict__ kern,
    short* __restrict__ qw, float* __restrict__ qterm, short* __restrict__ wcb)
{
    const int tid  = threadIdx.x;
    const int lane = tid & 63;
    const int row  = blockIdx.x * 4 + (tid >> 6);   // 0..2047 (b*128 + j)
    const int k0   = lane * 8;
    const float* qr = q + (size_t)row * D_;
    f32x4 a0 = *(const f32x4*)(qr + k0);
    f32x4 a1 = *(const f32x4*)(qr + k0 + 4);
    f32x4 c0 = *(const f32x4*)(kern + 2 * D_ + k0);      // w_cq
    f32x4 c1 = *(const f32x4*)(kern + 2 * D_ + k0 + 4);
    f32x4 w0 = *(const f32x4*)(kern + D_ + k0);          // w_q
    f32x4 w1 = *(const f32x4*)(kern + D_ + k0 + 4);
    bf16x8 o;
    o[0] = f2bf(a0[0] * c0[0]); o[1] = f2bf(a0[1] * c0[1]);
    o[2] = f2bf(a0[2] * c0[2]); o[3] = f2bf(a0[3] * c0[3]);
    o[4] = f2bf(a1[0] * c1[0]); o[5] = f2bf(a1[1] * c1[1]);
    o[6] = f2bf(a1[2] * c1[2]); o[7] = f2bf(a1[3] * c1[3]);
    *(bf16x8*)(qw + (size_t)row * D_ + k0) = o;
    float s = a0[0]*w0[0] + a0[1]*w0[1] + a0[2]*w0[2] + a0[3]*w0[3]
            + a1[0]*w1[0] + a1[1]*w1[1] + a1[2]*w1[2] + a1[3]*w1[3];
    s += __shfl_xor(s, 1);  s += __shfl_xor(s, 2);  s += __shfl_xor(s, 4);
    s += __shfl_xor(s, 8);  s += __shfl_xor(s, 16); s += __shfl_xor(s, 32);
    if (lane == 0) qterm[row] = s;
    if (blockIdx.x == 0) {          // w_c -> bf16, once
        wcb[tid]       = f2bf(kern[tid]);
        wcb[tid + 256] = f2bf(kern[tid + 256]);
    }
}

// Main: out[b][i][j] = (c[b][i] . qw[b][j]) + cterm[b][i] + qterm[b][j] + bias
// Block: 32 rows x 128 cols; 8 waves as 2(M) x 4(N); wave tile 16x32.
// 512 threads, __launch_bounds__(512,4) -> 2 blocks/CU = 16 waves/CU = 4 waves/SIMD.
// Depth-3 register software pipeline (ring-4, fully unrolled -> static indices).
__global__ __launch_bounds__(512, 4) void sim_kernel(
    const float* __restrict__ c, const short* __restrict__ qw,
    const float* __restrict__ qterm, const short* __restrict__ wcb,
    const float* __restrict__ bias_p, float* __restrict__ out)
{
    const int bid  = blockIdx.x;
    const int b    = bid >> 5;          // 32 M-tiles per batch
    const int mt   = bid & 31;
    const int tid  = threadIdx.x;
    const int lane = tid & 63;
    const int wid  = tid >> 6;          // 0..7
    const int wm   = wid >> 2;          // wave row 0..1
    const int wn   = wid & 3;           // wave col 0..3
    const int rif  = lane & 15;         // row/col within 16x16 frag
    const int kg   = lane >> 4;         // k-group 0..3 (8 k-elems each)

    const int rowbase = mt * 32 + wm * 16;
    const float* cA = c   + ((size_t)(b * NC_ + rowbase + rif)) * D_ + kg * 8;
    const short* qB = qw  + ((size_t)(b * NQ_ + wn * 32 + rif)) * D_ + kg * 8;
    const short* wB = wcb + kg * 8;

    f32x4 acc0 = {}, acc1 = {}, accx = {};

    // ring-4 pipeline stages (A fp32 pair, 2 B frags, w_c frag): ~20 VGPR/stage
    f32x4 a0[4], a1[4];
    bf16x8 b0[4], b1[4], w8[4];

    #pragma unroll
    for (int s = 0; s < 3; ++s) {       // prologue: stages 0..2 (k = 0,32,64)
        const int k = s * 32;
        a0[s] = *(const f32x4*)(cA + k);
        a1[s] = *(const f32x4*)(cA + k + 4);
        b0[s] = *(const bf16x8*)(qB + k);
        b1[s] = *(const bf16x8*)(qB + k + 16 * D_);
        w8[s] = *(const bf16x8*)(wB + k);
    }

    #pragma unroll
    for (int it = 0; it < 16; ++it) {
        const int cur = it & 3;
        if (it + 3 < 16) {              // prefetch 3 iterations ahead
            const int nxt = (it + 3) & 3;
            const int k = (it + 3) * 32;
            a0[nxt] = *(const f32x4*)(cA + k);
            a1[nxt] = *(const f32x4*)(cA + k + 4);
            b0[nxt] = *(const bf16x8*)(qB + k);
            b1[nxt] = *(const bf16x8*)(qB + k + 16 * D_);
            w8[nxt] = *(const bf16x8*)(wB + k);
        }
        bf16x8 af;
        af[0] = f2bf(a0[cur][0]); af[1] = f2bf(a0[cur][1]);
        af[2] = f2bf(a0[cur][2]); af[3] = f2bf(a0[cur][3]);
        af[4] = f2bf(a1[cur][0]); af[5] = f2bf(a1[cur][1]);
        af[6] = f2bf(a1[cur][2]); af[7] = f2bf(a1[cur][3]);
        acc0 = __builtin_amdgcn_mfma_f32_16x16x32_bf16(af, b0[cur], acc0, 0, 0, 0);
        acc1 = __builtin_amdgcn_mfma_f32_16x16x32_bf16(af, b1[cur], acc1, 0, 0, 0);
        if (wn == 0)    // cterm: every B-column = w_c slice -> D[i][*] = cterm[i]
            accx = __builtin_amdgcn_mfma_f32_16x16x32_bf16(af, w8[cur], accx, 0, 0, 0);
    }

    __shared__ float ct[32];
    if (wn == 0 && rif == 0) {
        ct[wm * 16 + kg * 4 + 0] = accx[0];
        ct[wm * 16 + kg * 4 + 1] = accx[1];
        ct[wm * 16 + kg * 4 + 2] = accx[2];
        ct[wm * 16 + kg * 4 + 3] = accx[3];
    }
    __syncthreads();

    const float bias = *bias_p;
    const float* qt = qterm + b * NQ_ + wn * 32 + rif;
    const float qt0 = qt[0], qt1 = qt[16];
    float* o = out + ((size_t)(b * NC_ + rowbase + kg * 4)) * NQ_ + wn * 32 + rif;
    #pragma unroll
    for (int r = 0; r < 4; ++r) {
        const float base = ct[wm * 16 + kg * 4 + r] + bias;
        o[(size_t)r * NQ_ +  0] = acc0[r] + base + qt0;
        o[(size_t)r * NQ_ + 16] = acc1[r] + base + qt1;
    }
}

extern "C" void kernel_launch(void* const* d_in, const int* in_sizes, int n_in,
                              void* d_out, int out_size, void* d_ws, size_t ws_size,
                              hipStream_t stream) {
    const float* c    = (const float*)d_in[0];
    const float* q    = (const float*)d_in[1];
    const float* kern = (const float*)d_in[2];
    const float* bias = (const float*)d_in[3];
    float* out = (float*)d_out;

    // ws layout: qw bf16 [2048][512] (2 MiB) | qterm f32 [2048] | wcb bf16 [512]
    short* qw    = (short*)d_ws;
    float* qterm = (float*)((char*)d_ws + (size_t)2048 * 512 * 2);
    short* wcb   = (short*)((char*)d_ws + (size_t)2048 * 512 * 2 + 2048 * 4);

    prep_kernel<<<512, 256, 0, stream>>>(q, kern, qw, qterm, wcb);
    sim_kernel<<<512, 512, 0, stream>>>(c, qw, qterm, wcb, bias, out);   // 512 threads (8 waves) — R2 bug was 256 here
}

// Round 4
// 40.536 us; speedup vs baseline: 1.0602x; 1.0602x over previous
//
#include <hip/hip_runtime.h>
#include <hip/hip_bf16.h>

#define B_   16
#define NC_  1024
#define NQ_  128
#define D_   512

typedef __attribute__((ext_vector_type(8))) short bf16x8;
typedef __attribute__((ext_vector_type(4))) float f32x4;

// fp32 -> bf16 RTNE; scalar cast so compiler fuses pairs into v_cvt_pk_bf16_f32
__device__ __forceinline__ short f2bf(float x) {
    return __builtin_bit_cast(short, __float2bfloat16(x));
}

// Pre-kernel: qw[b][j][d] = bf16(q*w_cq + w_c)  (c_term folded into the GEMM B!)
//             qterm[b][j] = q . w_q (fp32)
__global__ __launch_bounds__(256) void prep_kernel(
    const float* __restrict__ q, const float* __restrict__ kern,
    short* __restrict__ qw, float* __restrict__ qterm)
{
    const int tid  = threadIdx.x;
    const int lane = tid & 63;
    const int row  = blockIdx.x * 4 + (tid >> 6);   // 0..2047 (b*128 + j)
    const int k0   = lane * 8;
    const float* qr = q + (size_t)row * D_;
    f32x4 a0 = *(const f32x4*)(qr + k0);
    f32x4 a1 = *(const f32x4*)(qr + k0 + 4);
    f32x4 g0 = *(const f32x4*)(kern + 2 * D_ + k0);      // w_cq
    f32x4 g1 = *(const f32x4*)(kern + 2 * D_ + k0 + 4);
    f32x4 w0 = *(const f32x4*)(kern + D_ + k0);          // w_q
    f32x4 w1 = *(const f32x4*)(kern + D_ + k0 + 4);
    f32x4 h0 = *(const f32x4*)(kern + k0);               // w_c
    f32x4 h1 = *(const f32x4*)(kern + k0 + 4);
    bf16x8 o;
    o[0] = f2bf(a0[0] * g0[0] + h0[0]); o[1] = f2bf(a0[1] * g0[1] + h0[1]);
    o[2] = f2bf(a0[2] * g0[2] + h0[2]); o[3] = f2bf(a0[3] * g0[3] + h0[3]);
    o[4] = f2bf(a1[0] * g1[0] + h1[0]); o[5] = f2bf(a1[1] * g1[1] + h1[1]);
    o[6] = f2bf(a1[2] * g1[2] + h1[2]); o[7] = f2bf(a1[3] * g1[3] + h1[3]);
    *(bf16x8*)(qw + (size_t)row * D_ + k0) = o;
    float s = a0[0]*w0[0] + a0[1]*w0[1] + a0[2]*w0[2] + a0[3]*w0[3]
            + a1[0]*w1[0] + a1[1]*w1[1] + a1[2]*w1[2] + a1[3]*w1[3];
    s += __shfl_xor(s, 1);  s += __shfl_xor(s, 2);  s += __shfl_xor(s, 4);
    s += __shfl_xor(s, 8);  s += __shfl_xor(s, 16); s += __shfl_xor(s, 32);
    if (lane == 0) qterm[row] = s;
}

// Main: out[b][i][j] = (c[b][i] . qw[b][j]) + qterm[b][j] + bias
//   (qw already contains w_c, so the MFMA produces cq_term + c_term)
// Block: 256 threads = 4 waves, ALL on the same 16 A-rows (BM=16), wn=0..3 col slices.
// Grid: 16 batches x 64 M-tiles = 1024 blocks -> 4 blocks/CU = 4 waves/SIMD.
// Ring-4 register pipeline, prefetch distance 3; ~95 VGPR live -> fits 128 cap.
__global__ __launch_bounds__(256, 4) void sim_kernel(
    const float* __restrict__ c, const short* __restrict__ qw,
    const float* __restrict__ qterm,
    const float* __restrict__ bias_p, float* __restrict__ out)
{
    const int bid  = blockIdx.x;
    const int b    = bid >> 6;          // 64 M-tiles per batch
    const int mt   = bid & 63;
    const int tid  = threadIdx.x;
    const int lane = tid & 63;
    const int wn   = tid >> 6;          // wave col 0..3
    const int rif  = lane & 15;         // row/col within 16x16 frag
    const int kg   = lane >> 4;         // k-group 0..3 (8 k-elems each)

    const int rowbase = mt * 16;
    const float* cA = c  + ((size_t)(b * NC_ + rowbase + rif)) * D_ + kg * 8;
    const short* qB = qw + ((size_t)(b * NQ_ + wn * 32 + rif)) * D_ + kg * 8;

    f32x4 acc0 = {}, acc1 = {};

    // ring-4 pipeline stages (A fp32 pair + 2 B frags = 16 VGPR/stage)
    f32x4 a0[4], a1[4];
    bf16x8 b0[4], b1[4];

    #pragma unroll
    for (int s = 0; s < 3; ++s) {       // prologue: k = 0,32,64
        const int k = s * 32;
        a0[s] = *(const f32x4*)(cA + k);
        a1[s] = *(const f32x4*)(cA + k + 4);
        b0[s] = *(const bf16x8*)(qB + k);
        b1[s] = *(const bf16x8*)(qB + k + 16 * D_);
    }

    #pragma unroll
    for (int it = 0; it < 16; ++it) {
        const int cur = it & 3;
        if (it + 3 < 16) {              // prefetch 3 iterations ahead
            const int nxt = (it + 3) & 3;
            const int k = (it + 3) * 32;
            a0[nxt] = *(const f32x4*)(cA + k);
            a1[nxt] = *(const f32x4*)(cA + k + 4);
            b0[nxt] = *(const bf16x8*)(qB + k);
            b1[nxt] = *(const bf16x8*)(qB + k + 16 * D_);
        }
        bf16x8 af;
        af[0] = f2bf(a0[cur][0]); af[1] = f2bf(a0[cur][1]);
        af[2] = f2bf(a0[cur][2]); af[3] = f2bf(a0[cur][3]);
        af[4] = f2bf(a1[cur][0]); af[5] = f2bf(a1[cur][1]);
        af[6] = f2bf(a1[cur][2]); af[7] = f2bf(a1[cur][3]);
        acc0 = __builtin_amdgcn_mfma_f32_16x16x32_bf16(af, b0[cur], acc0, 0, 0, 0);
        acc1 = __builtin_amdgcn_mfma_f32_16x16x32_bf16(af, b1[cur], acc1, 0, 0, 0);
    }

    const float bias = *bias_p;
    const float* qt = qterm + b * NQ_ + wn * 32 + rif;
    const float base0 = qt[0]  + bias;
    const float base1 = qt[16] + bias;
    float* o = out + ((size_t)(b * NC_ + rowbase + kg * 4)) * NQ_ + wn * 32 + rif;
    #pragma unroll
    for (int r = 0; r < 4; ++r) {
        o[(size_t)r * NQ_ +  0] = acc0[r] + base0;
        o[(size_t)r * NQ_ + 16] = acc1[r] + base1;
    }
}

extern "C" void kernel_launch(void* const* d_in, const int* in_sizes, int n_in,
                              void* d_out, int out_size, void* d_ws, size_t ws_size,
                              hipStream_t stream) {
    const float* c    = (const float*)d_in[0];
    const float* q    = (const float*)d_in[1];
    const float* kern = (const float*)d_in[2];
    const float* bias = (const float*)d_in[3];
    float* out = (float*)d_out;

    // ws layout: qw bf16 [2048][512] (2 MiB) | qterm f32 [2048]
    short* qw    = (short*)d_ws;
    float* qterm = (float*)((char*)d_ws + (size_t)2048 * 512 * 2);

    prep_kernel<<<512, 256, 0, stream>>>(q, kern, qw, qterm);   // 2048 rows / 4 per block
    sim_kernel<<<1024, 256, 0, stream>>>(c, qw, qterm, bias, out);  // 16 batches x 64 tiles, 256 thr
}